// Round 10
// baseline (114.212 us; speedup 1.0000x reference)
//
#include <hip/hip_runtime.h>
#include <math.h>

typedef short short8 __attribute__((ext_vector_type(8)));
typedef float f32x4  __attribute__((ext_vector_type(4)));

constexpr int Ssz = 512, Dsz = 64, Lsz = 4, Bsz = 32;
constexpr int TI = 16, TJ = 64;   // i-tile 16 -> 1024 blocks -> 4 blocks/CU

// Main-phase LDS (shorts), dense tiles + 16B-granule XOR swizzle (g ^= row&7):
constexpr int XT16 = 0;                        // X^T [64 d][64 j] bf16
constexpr int AI16 = 64 * 64;                  // 4 x [16 i][64 j]: AI[l][i][j] = A[j0+j][i0+i]
constexpr int AO16 = AI16 + 4 * 16 * 64;       // 4 x [16 i][64 j]: AO[l][i][j] = A[i0+i][j0+j]
constexpr int SMEM_BYTES = (AO16 + 4 * 16 * 64) * 2;   // 24576 B -> 4+ blocks/CU

// epilogue overlay (float-indexed; main tiles dead by then; 22.4 KB < 24 KB)
constexpr int YBs = 69;                        // 69 == 5 mod 32 -> conflict-free
constexpr int YB_f = 0;                        // [16][69] f32
constexpr int WBs = 68;
constexpr int WB_f = YB_f + 16 * YBs;          // [64][68] f32
constexpr int DG_f = WB_f + 64 * WBs;          // [16] deg
constexpr int WG_f = DG_f + 16;                // [64] gate weights
constexpr int BB_f = WG_f + 64;                // [64] bias

__device__ __forceinline__ unsigned short f2bf(float x) {
    union { float f; unsigned u; } v; v.f = x;
    unsigned r = v.u + 0x7FFFu + ((v.u >> 16) & 1u);   // RNE
    return (unsigned short)(r >> 16);
}

__global__ __launch_bounds__(512, 4)
void rfgcn_mfma(const float* __restrict__ X,      // [B][S][D]
                const int*   __restrict__ adj,    // [L][B][S][S]
                const float* __restrict__ nw,     // [B]
                const float* __restrict__ W_in,   // [L][D][D]
                const float* __restrict__ b_in,   // [L][D]
                const float* __restrict__ wg_in,  // [L][D]
                const float* __restrict__ bg_in,  // [L]
                const float* __restrict__ W_out,
                const float* __restrict__ b_out,
                const float* __restrict__ wg_out,
                const float* __restrict__ bg_out,
                float* __restrict__ out)
{
    __shared__ __align__(16) char smem[SMEM_BYTES];
    short* sm16 = (short*)smem;
    float* smf  = (float*)smem;

    const int tid  = threadIdx.x;
    const int b    = blockIdx.y;
    const int i0   = blockIdx.x * TI;
    const int w    = tid >> 6;       // wave 0..7
    const int lane = tid & 63;
    const int dir  = w & 1;          // 0 = in (A^T), 1 = out (A)
    const int wl   = w >> 1;         // label 0..3 owned by this wave
    const int lm   = lane & 15;
    const int lg   = lane >> 4;      // k-group 0..3

    f32x4 acc[4];                    // n-tiles (cols nt*16..)
    f32x4 dacc;                      // degree accumulator
#pragma unroll
    for (int nt = 0; nt < 4; ++nt) acc[nt] = (f32x4){0.f, 0.f, 0.f, 0.f};
    dacc = (f32x4){0.f, 0.f, 0.f, 0.f};
    const short8 ones = {(short)0x3F80, (short)0x3F80, (short)0x3F80, (short)0x3F80,
                         (short)0x3F80, (short)0x3F80, (short)0x3F80, (short)0x3F80};

    const float* Xb = X + (size_t)b * Ssz * Dsz;

    for (int jc = 0; jc < Ssz / TJ; ++jc) {
        const int j0 = jc * TJ;
        __syncthreads();   // previous chunk's fragment reads done

        // ---- stage X^T bf16: thread owns col d=lane, rows j0+8w..+7 (coalesced)
        {
            const int d = lane;
            float xv[8];
#pragma unroll
            for (int s = 0; s < 8; ++s) xv[s] = Xb[(size_t)(j0 + 8 * w + s) * Dsz + d];
            short8 hi;
#pragma unroll
            for (int s = 0; s < 8; ++s) hi[s] = (short)f2bf(xv[s]);
            const int g = w ^ (d & 7);
            *(short8*)(sm16 + XT16 + d * 64 + g * 8) = hi;
        }
        // ---- stage AI (transposed): thread owns col i=tid&15, j-pair jp=tid>>4
#pragma unroll
        for (int l = 0; l < Lsz; ++l) {
            const int* Ab = adj + ((size_t)l * Bsz + b) * Ssz * Ssz;
            const int ii = tid & 15, jp = tid >> 4;   // jp 0..31
            const int a0 = Ab[(size_t)(j0 + 2 * jp)     * Ssz + i0 + ii];
            const int a1 = Ab[(size_t)(j0 + 2 * jp + 1) * Ssz + i0 + ii];
            const unsigned pack = (a0 ? 0x3F80u : 0u) | (a1 ? 0x3F800000u : 0u);
            const int g = (jp >> 2) ^ (ii & 7);
            *(unsigned*)(sm16 + AI16 + l * 1024 + ii * 64 + g * 8 + (2 * jp & 7)) = pack;
        }
        // ---- stage AO (direct): thread owns row r=tid>>5, j-pair cp=tid&31
#pragma unroll
        for (int l = 0; l < Lsz; ++l) {
            const int* Ab = adj + ((size_t)l * Bsz + b) * Ssz * Ssz;
            const int r = tid >> 5, cp = tid & 31;
            const int2 p = *(const int2*)&Ab[(size_t)(i0 + r) * Ssz + j0 + 2 * cp];
            const unsigned pack = (p.x ? 0x3F80u : 0u) | (p.y ? 0x3F800000u : 0u);
            const int g = (cp >> 2) ^ (r & 7);
            *(unsigned*)(sm16 + AO16 + l * 1024 + r * 64 + g * 8 + (2 * cp & 7)) = pack;
        }
        __syncthreads();

        // ---- 2 K-steps of 32: wave owns (dir, label wl), rows i0..i0+15
#pragma unroll
        for (int ks = 0; ks < 2; ++ks) {
            short8 bh[4];
#pragma unroll
            for (int nt = 0; nt < 4; ++nt) {
                const int d = nt * 16 + lm;
                const int g = (4 * ks + lg) ^ (d & 7);
                bh[nt] = *(const short8*)(sm16 + XT16 + d * 64 + g * 8);
            }
            const int ga = (4 * ks + lg) ^ (lm & 7);
            const short8 af = *(const short8*)(sm16 + (dir ? AO16 : AI16) + wl * 1024 + lm * 64 + ga * 8);
#pragma unroll
            for (int nt = 0; nt < 4; ++nt)
                acc[nt] = __builtin_amdgcn_mfma_f32_16x16x32_bf16(af, bh[nt], acc[nt], 0, 0, 0);
            dacc = __builtin_amdgcn_mfma_f32_16x16x32_bf16(af, ones, dacc, 0, 0, 0);
        }
    }

    // ======== epilogue: t = Y*W + deg*b; gate = Y*wg + deg*bg; fin += t*sigmoid(gate)
    const int ei = tid >> 5;          // output row 0..15
    const int ec = tid & 31;          // 2-col group (cols 2ec, 2ec+1) — coalesced I/O
    float fin0 = 0.f, fin1 = 0.f;

#pragma unroll
    for (int l = 0; l < Lsz; ++l) {
#pragma unroll
        for (int d2 = 0; d2 < 2; ++d2) {
            __syncthreads();   // previous consumers done before overwrite
            if (dir == d2 && wl == l) {   // owning wave writes its Y (C-layout)
#pragma unroll
                for (int nt = 0; nt < 4; ++nt)
#pragma unroll
                    for (int r = 0; r < 4; ++r)
                        smf[YB_f + (4 * lg + r) * YBs + nt * 16 + lm] = acc[nt][r];
                if (lm == 0)
#pragma unroll
                    for (int r = 0; r < 4; ++r)
                        smf[DG_f + 4 * lg + r] = dacc[r];
            }
            // stage W (all threads, coalesced float4)
            const float* Wp = (d2 ? W_out : W_in) + l * Dsz * Dsz;
            {
                const int r = tid >> 3, c8 = tid & 7;
                *(float4*)&smf[WB_f + r * WBs + 8 * c8]     = *(const float4*)&Wp[r * Dsz + 8 * c8];
                *(float4*)&smf[WB_f + r * WBs + 8 * c8 + 4] = *(const float4*)&Wp[r * Dsz + 8 * c8 + 4];
            }
            const float* wgp = (d2 ? wg_out : wg_in) + l * Dsz;
            const float* bp  = (d2 ? b_out  : b_in)  + l * Dsz;
            if (tid < 64)        smf[WG_f + tid]      = wgp[tid];
            else if (tid < 128)  smf[BB_f + tid - 64] = bp[tid - 64];
            const float bgs = (d2 ? bg_out : bg_in)[l];
            __syncthreads();

            const float dg = smf[DG_f + ei];
            float t0 = dg * smf[BB_f + 2 * ec];
            float t1 = dg * smf[BB_f + 2 * ec + 1];
            float gate = dg * bgs;
#pragma unroll 8
            for (int e = 0; e < 64; ++e) {
                const float yv = smf[YB_f + ei * YBs + e];   // broadcast within half-wave
                gate += yv * smf[WG_f + e];
                const float2 wv = *(const float2*)&smf[WB_f + e * WBs + 2 * ec];
                t0 += yv * wv.x;
                t1 += yv * wv.y;
            }
            const float sg = 1.f / (1.f + expf(-gate));
            fin0 += t0 * sg;
            fin1 += t1 * sg;
        }
    }

    const float inv = 1.f / (3.f * nw[b]);
    const float2 xv = *(const float2*)&Xb[(size_t)(i0 + ei) * Dsz + 2 * ec];
    float2 o;
    o.x = (xv.x + fin0) * inv;
    o.y = (xv.y + fin1) * inv;
    *(float2*)(out + ((size_t)b * Ssz + i0 + ei) * Dsz + 2 * ec) = o;
}

extern "C" void kernel_launch(void* const* d_in, const int* in_sizes, int n_in,
                              void* d_out, int out_size, void* d_ws, size_t ws_size,
                              hipStream_t stream)
{
    const float* X      = (const float*)d_in[0];
    const int*   adj    = (const int*)  d_in[1];
    const float* nw     = (const float*)d_in[2];
    const float* W_in   = (const float*)d_in[3];
    const float* b_in   = (const float*)d_in[4];
    const float* wg_in  = (const float*)d_in[5];
    const float* bg_in  = (const float*)d_in[6];
    const float* W_out  = (const float*)d_in[7];
    const float* b_out  = (const float*)d_in[8];
    const float* wg_out = (const float*)d_in[9];
    const float* bg_out = (const float*)d_in[10];
    float* out = (float*)d_out;

    dim3 grid(Ssz / TI, Bsz);   // (32, 32) = 1024 blocks -> 4 blocks/CU
    dim3 block(512);
    hipLaunchKernelGGL(rfgcn_mfma, grid, block, 0, stream,
                       X, adj, nw, W_in, b_in, wg_in, bg_in,
                       W_out, b_out, wg_out, bg_out, out);
}

// Round 11
// 92.256 us; speedup vs baseline: 1.2380x; 1.2380x over previous
//
#include <hip/hip_runtime.h>
#include <math.h>

typedef short short8 __attribute__((ext_vector_type(8)));
typedef short s16x4  __attribute__((ext_vector_type(4)));
typedef float f32x4  __attribute__((ext_vector_type(4)));

constexpr int Ssz = 512, Dsz = 64, Lsz = 4, Bsz = 32;
constexpr int TI = 32, TJ = 64;   // round-8 geometry (verified best)

// Main-phase LDS (shorts), dense tiles + 16B-granule XOR swizzle (g ^= row&7)
constexpr int XT16 = 0;                          // X^T [64 d][64 j] bf16
constexpr int AI16 = 64 * 64;                    // 4 x [32 i][64 j]: AI[l][i][j] = A[j0+j][i0+i]
constexpr int AO16 = AI16 + 4 * 32 * 64;         // 4 x [32 i][64 j]: AO[l][i][j] = A[i0+i][j0+j]
constexpr int MAIN_B = (AO16 + 4 * 32 * 64) * 2; // 40960 B
// Epilogue: Y slices (8 x [32][64] bf16 = 32768 B) OVERLAY the main region.
// deg + fin live outside it:
constexpr int DEG_B = MAIN_B;                    // 8 waves x 32 f32 = 1024 B
constexpr int FIN_B = DEG_B + 1024;              // [64 c][33 i] f32 = 8448 B (pad 33 -> conflict-free)
constexpr int SMEM_BYTES = FIN_B + 8448;         // 50432 B

__device__ __forceinline__ unsigned short f2bf(float x) {
    union { float f; unsigned u; } v; v.f = x;
    unsigned r = v.u + 0x7FFFu + ((v.u >> 16) & 1u);   // RNE
    return (unsigned short)(r >> 16);
}

__global__ __launch_bounds__(512, 4)
void rfgcn_mfma(const float* __restrict__ X,      // [B][S][D]
                const int*   __restrict__ adj,    // [L][B][S][S]
                const float* __restrict__ nw,     // [B]
                const float* __restrict__ W_in,   // [L][D][D] (row = e = d_in)
                const float* __restrict__ b_in,   // [L][D]
                const float* __restrict__ wg_in,  // [L][D]
                const float* __restrict__ bg_in,  // [L]
                const float* __restrict__ W_out,
                const float* __restrict__ b_out,
                const float* __restrict__ wg_out,
                const float* __restrict__ bg_out,
                float* __restrict__ out)
{
    __shared__ __align__(16) char smem[SMEM_BYTES];
    short* sm16 = (short*)smem;
    float* degf = (float*)(smem + DEG_B);
    float* finf = (float*)(smem + FIN_B);

    const int tid  = threadIdx.x;
    const int b    = blockIdx.y;
    const int i0   = blockIdx.x * TI;
    const int w    = tid >> 6;       // wave 0..7
    const int lane = tid & 63;
    const int dir  = w & 1;          // 0 = in (A^T), 1 = out (A)
    const int wl   = w >> 1;         // label 0..3 owned by this wave
    const int lm   = lane & 15;
    const int lg   = lane >> 4;      // k-group 0..3

    f32x4 acc[2][4];                 // [row-tile rt][e-tile nt]
    f32x4 dacc[2];                   // degree per row-tile
#pragma unroll
    for (int rt = 0; rt < 2; ++rt) {
#pragma unroll
        for (int nt = 0; nt < 4; ++nt) acc[rt][nt] = (f32x4){0.f, 0.f, 0.f, 0.f};
        dacc[rt] = (f32x4){0.f, 0.f, 0.f, 0.f};
    }
    const short8 ones = {(short)0x3F80, (short)0x3F80, (short)0x3F80, (short)0x3F80,
                         (short)0x3F80, (short)0x3F80, (short)0x3F80, (short)0x3F80};

    // zero fin accumulation buffer (used only after BAR1; first barrier covers visibility)
    for (int k = tid; k < 64 * 33; k += 512) finf[k] = 0.f;

    const float* Xb = X + (size_t)b * Ssz * Dsz;

    // ===================== main loop: Y = A_dir · X  (per wave: one (dir,label)) =====
    for (int jc = 0; jc < Ssz / TJ; ++jc) {
        const int j0 = jc * TJ;
        __syncthreads();   // previous chunk's fragment reads done

        // ---- stage X^T bf16: thread owns col d=lane, rows j0+8w..+7 (coalesced)
        {
            const int d = lane;
            float xv[8];
#pragma unroll
            for (int s = 0; s < 8; ++s) xv[s] = Xb[(size_t)(j0 + 8 * w + s) * Dsz + d];
            short8 hi;
#pragma unroll
            for (int s = 0; s < 8; ++s) hi[s] = (short)f2bf(xv[s]);
            const int g = w ^ (d & 7);
            *(short8*)(sm16 + XT16 + d * 64 + g * 8) = hi;
        }
        // ---- stage AI (transposed): thread owns col i=tid&31, j-quad jq=tid>>5
#pragma unroll
        for (int l = 0; l < Lsz; ++l) {
            const int* Ab = adj + ((size_t)l * Bsz + b) * Ssz * Ssz;
            const int ii = tid & 31, jq = tid >> 5;   // jq 0..15
            int iv[4];
#pragma unroll
            for (int s = 0; s < 4; ++s) iv[s] = Ab[(size_t)(j0 + 4 * jq + s) * Ssz + i0 + ii];
            s16x4 v;
#pragma unroll
            for (int s = 0; s < 4; ++s) v[s] = iv[s] ? (short)0x3F80 : (short)0;
            const int g = (jq >> 1) ^ (ii & 7);
            *(s16x4*)(sm16 + AI16 + l * 2048 + ii * 64 + g * 8 + (jq & 1) * 4) = v;
        }
        // ---- stage AO (direct): thread owns row r=tid>>4, j-quad c4=tid&15
#pragma unroll
        for (int l = 0; l < Lsz; ++l) {
            const int* Ab = adj + ((size_t)l * Bsz + b) * Ssz * Ssz;
            const int r = tid >> 4, c4 = tid & 15;
            const int4 p = *(const int4*)&Ab[(size_t)(i0 + r) * Ssz + j0 + 4 * c4];
            s16x4 v;
            v[0] = p.x ? (short)0x3F80 : (short)0;  v[1] = p.y ? (short)0x3F80 : (short)0;
            v[2] = p.z ? (short)0x3F80 : (short)0;  v[3] = p.w ? (short)0x3F80 : (short)0;
            const int g = (c4 >> 1) ^ (r & 7);
            *(s16x4*)(sm16 + AO16 + l * 2048 + r * 64 + g * 8 + (c4 & 1) * 4) = v;
        }
        __syncthreads();

        // ---- 2 K-steps of 32
#pragma unroll
        for (int ks = 0; ks < 2; ++ks) {
            short8 bh[4];
#pragma unroll
            for (int nt = 0; nt < 4; ++nt) {
                const int d = nt * 16 + lm;
                const int g = (4 * ks + lg) ^ (d & 7);
                bh[nt] = *(const short8*)(sm16 + XT16 + d * 64 + g * 8);
            }
            short8 af[2];
#pragma unroll
            for (int rt = 0; rt < 2; ++rt) {
                const int il = 16 * rt + lm;
                const int ga = (4 * ks + lg) ^ (il & 7);
                af[rt] = *(const short8*)(sm16 + (dir ? AO16 : AI16) + wl * 2048 + il * 64 + ga * 8);
            }
#pragma unroll
            for (int rt = 0; rt < 2; ++rt) {
#pragma unroll
                for (int nt = 0; nt < 4; ++nt)
                    acc[rt][nt] = __builtin_amdgcn_mfma_f32_16x16x32_bf16(af[rt], bh[nt], acc[rt][nt], 0, 0, 0);
                dacc[rt] = __builtin_amdgcn_mfma_f32_16x16x32_bf16(af[rt], ones, dacc[rt], 0, 0, 0);
            }
        }
    }

    // ===================== MFMA epilogue: T^T = W'^T · Y^T, per-wave independent =====
    __syncthreads();   // BAR1: all waves done reading main tiles; Y slices overlay them

    // 1) write wave-private Y slice [32 rows][64 e] bf16, 16B-granule swizzle (^row&7)
    short* Ys = sm16 + w * 2048;
#pragma unroll
    for (int rt = 0; rt < 2; ++rt)
#pragma unroll
        for (int nt = 0; nt < 4; ++nt)
#pragma unroll
            for (int r = 0; r < 4; ++r) {
                const int row = 16 * rt + 4 * lg + r;           // i
                const int gs  = (((2 * nt + (lm >> 3)) ^ (row & 7)) << 3) + (lm & 7);
                Ys[row * 64 + gs] = (short)f2bf(acc[rt][nt][r]); // e = 16*nt+lm
            }
    if (lm == 0) {
#pragma unroll
        for (int rt = 0; rt < 2; ++rt)
#pragma unroll
            for (int r = 0; r < 4; ++r)
                degf[w * 32 + 16 * rt + 4 * lg + r] = dacc[rt][r];
    }

    // 2) read Y^T B-fragments: lane holds B[n=i=lm+16it][k=e=8lg+j+32ks]
    short8 by[2][2];
#pragma unroll
    for (int it = 0; it < 2; ++it)
#pragma unroll
        for (int ks = 0; ks < 2; ++ks) {
            const int i  = 16 * it + lm;
            const int gs = ((lg + 4 * ks) ^ (i & 7)) << 3;
            by[it][ks] = *(const short8*)(Ys + i * 64 + gs);
        }
    float degv[2];
#pragma unroll
    for (int it = 0; it < 2; ++it) degv[it] = degf[w * 32 + 16 * it + lm];

    // 3) A-fragments of W'^T straight from global (L2-hot), MFMA into accT
    const float* Wp  = (dir ? W_out  : W_in)  + wl * Dsz * Dsz;
    const float* wgp = (dir ? wg_out : wg_in) + wl * Dsz;
    const float* bp  = (dir ? b_out  : b_in)  + wl * Dsz;
    const float  bgv = (dir ? bg_out : bg_in)[wl];

    f32x4 accT[5][2];   // [c-tile ct (ct=4 -> gate)][i-tile it]
#pragma unroll
    for (int ct = 0; ct < 5; ++ct)
#pragma unroll
        for (int it = 0; it < 2; ++it) accT[ct][it] = (f32x4){0.f, 0.f, 0.f, 0.f};

#pragma unroll
    for (int ct = 0; ct < 5; ++ct) {
#pragma unroll
        for (int ks = 0; ks < 2; ++ks) {
            short8 aw;
            if (ct < 4) {
                const int c = 16 * ct + lm;
#pragma unroll
                for (int j = 0; j < 8; ++j)
                    aw[j] = (short)f2bf(Wp[(size_t)(8 * lg + j + 32 * ks) * Dsz + c]);
            } else {
#pragma unroll
                for (int j = 0; j < 8; ++j)
                    aw[j] = (short)f2bf(wgp[8 * lg + j + 32 * ks]);   // gate rows: wg replicated
            }
#pragma unroll
            for (int it = 0; it < 2; ++it)
                accT[ct][it] = __builtin_amdgcn_mfma_f32_16x16x32_bf16(aw, by[it][ks], accT[ct][it], 0, 0, 0);
        }
    }

    // 4) gate -> sigmoid; deg*b correction; atomic-accumulate fin^T[c][i]
    float sg[2];
#pragma unroll
    for (int it = 0; it < 2; ++it) {
        const float g = accT[4][it][0] + degv[it] * bgv;   // replicated over r
        sg[it] = 1.f / (1.f + expf(-g));
    }
#pragma unroll
    for (int ct = 0; ct < 4; ++ct)
#pragma unroll
        for (int r = 0; r < 4; ++r) {
            const int c = 16 * ct + 4 * lg + r;
            const float bc = bp[c];
#pragma unroll
            for (int it = 0; it < 2; ++it) {
                const float v = (accT[ct][it][r] + degv[it] * bc) * sg[it];
                atomicAdd(&finf[c * 33 + 16 * it + lm], v);
            }
        }

    __syncthreads();   // BAR2: fin complete

    // 5) writeout: out = (X + fin)/ (3*nw)
    const float inv = 1.f / (3.f * nw[b]);
    const int oi = tid >> 4;           // row 0..31
    const int c4 = (tid & 15) * 4;     // col group
    const float4 xv = *(const float4*)&Xb[(size_t)(i0 + oi) * Dsz + c4];
    float4 o;
    o.x = (xv.x + finf[(c4 + 0) * 33 + oi]) * inv;
    o.y = (xv.y + finf[(c4 + 1) * 33 + oi]) * inv;
    o.z = (xv.z + finf[(c4 + 2) * 33 + oi]) * inv;
    o.w = (xv.w + finf[(c4 + 3) * 33 + oi]) * inv;
    *(float4*)(out + ((size_t)b * Ssz + i0 + oi) * Dsz + c4) = o;
}

extern "C" void kernel_launch(void* const* d_in, const int* in_sizes, int n_in,
                              void* d_out, int out_size, void* d_ws, size_t ws_size,
                              hipStream_t stream)
{
    const float* X      = (const float*)d_in[0];
    const int*   adj    = (const int*)  d_in[1];
    const float* nw     = (const float*)d_in[2];
    const float* W_in   = (const float*)d_in[3];
    const float* b_in   = (const float*)d_in[4];
    const float* wg_in  = (const float*)d_in[5];
    const float* bg_in  = (const float*)d_in[6];
    const float* W_out  = (const float*)d_in[7];
    const float* b_out  = (const float*)d_in[8];
    const float* wg_out = (const float*)d_in[9];
    const float* bg_out = (const float*)d_in[10];
    float* out = (float*)d_out;

    dim3 grid(Ssz / TI, Bsz);   // (16, 32) = 512 blocks
    dim3 block(512);
    hipLaunchKernelGGL(rfgcn_mfma, grid, block, 0, stream,
                       X, adj, nw, W_in, b_in, wg_in, bg_in,
                       W_out, b_out, wg_out, bg_out, out);
}

// Round 12
// 76.148 us; speedup vs baseline: 1.4999x; 1.2115x over previous
//
#include <hip/hip_runtime.h>
#include <math.h>

typedef short s16x4  __attribute__((ext_vector_type(4)));
typedef short short8 __attribute__((ext_vector_type(8)));
typedef float f32x4  __attribute__((ext_vector_type(4)));

constexpr int Ssz = 512, Dsz = 64, Lsz = 4, Bsz = 32;
constexpr int TI = 32, TJ = 64;   // round-8 geometry (verified best: 77.9 us)

// Main-phase LDS: dense bf16 tiles, 16B-granule XOR swizzle (g ^= row&7).
constexpr int XT16 = 0;                          // X^T [64 d][64 j] bf16
constexpr int AI16 = 64 * 64;                    // 4 x [32 i][64 j]: AI[l][i][j] = A[j0+j][i0+i]
constexpr int AO16 = AI16 + 4 * 32 * 64;         // 4 x [32 i][64 j]: AO[l][i][j] = A[i0+i][j0+j]
constexpr int SMEM_BYTES = (AO16 + 4 * 32 * 64) * 2;   // 40960 B

// epilogue overlay (float-indexed; main tiles dead by then; 27.0 KB < 40 KB)
constexpr int YBs = 69;                          // 69 == 5 mod 32 -> conflict-free
constexpr int YB_f = 0;                          // [32][69] f32
constexpr int WBs = 68;
constexpr int WB_f = YB_f + 32 * YBs;            // [64][68] f32
constexpr int DG_f = WB_f + 64 * WBs;            // [32] deg
constexpr int WG_f = DG_f + 64;                  // [64] gate weights
constexpr int BB_f = WG_f + 64;                  // [64] bias

__device__ __forceinline__ unsigned short f2bf(float x) {
    union { float f; unsigned u; } v; v.f = x;
    unsigned r = v.u + 0x7FFFu + ((v.u >> 16) & 1u);   // RNE
    return (unsigned short)(r >> 16);
}

__global__ __launch_bounds__(512, 4)
void rfgcn_mfma(const float* __restrict__ X,      // [B][S][D]
                const int*   __restrict__ adj,    // [L][B][S][S]
                const float* __restrict__ nw,     // [B]
                const float* __restrict__ W_in,   // [L][D][D]
                const float* __restrict__ b_in,   // [L][D]
                const float* __restrict__ wg_in,  // [L][D]
                const float* __restrict__ bg_in,  // [L]
                const float* __restrict__ W_out,
                const float* __restrict__ b_out,
                const float* __restrict__ wg_out,
                const float* __restrict__ bg_out,
                float* __restrict__ out)
{
    __shared__ __align__(16) char smem[SMEM_BYTES];
    short* sm16 = (short*)smem;
    float* smf  = (float*)smem;

    const int tid  = threadIdx.x;
    const int b    = blockIdx.y;
    const int i0   = blockIdx.x * TI;
    const int w    = tid >> 6;        // wave 0..7
    const int lane = tid & 63;
    const int dir   = w & 1;          // 0 = in (A^T), 1 = out (A)
    const int strip = (w >> 1) & 1;   // 16-row strip 0..1
    const int lh    = w >> 2;         // label-half 0..1 (labels 2lh, 2lh+1)
    const int lm   = lane & 15;
    const int lg   = lane >> 4;       // k-group 0..3

    f32x4 acc[2][4];                  // [label-within-half][n-tile]
    f32x4 dacc[2];                    // degree accumulator
#pragma unroll
    for (int al = 0; al < 2; ++al) {
#pragma unroll
        for (int nt = 0; nt < 4; ++nt) acc[al][nt] = (f32x4){0.f, 0.f, 0.f, 0.f};
        dacc[al] = (f32x4){0.f, 0.f, 0.f, 0.f};
    }
    const short8 ones = {(short)0x3F80, (short)0x3F80, (short)0x3F80, (short)0x3F80,
                         (short)0x3F80, (short)0x3F80, (short)0x3F80, (short)0x3F80};

    const float* Xb = X + (size_t)b * Ssz * Dsz;

    // T14 prefetch registers (chunk t+1 in flight during chunk t's MFMA phase)
    float xv[8];
    int   aiv[4][4];
    int4  aov[4];
    // lane roles for staging (constant across chunks)
    const int ii = tid & 31, jq = tid >> 5;     // AI: col i, j-quad
    const int rr = tid >> 4, c4 = tid & 15;     // AO: row, j-quad

#define LOAD_CHUNK(J0)                                                            \
    {                                                                             \
        _Pragma("unroll")                                                         \
        for (int s = 0; s < 8; ++s) xv[s] = Xb[(size_t)((J0) + 8 * w + s) * Dsz + lane]; \
        _Pragma("unroll")                                                         \
        for (int l = 0; l < Lsz; ++l) {                                           \
            const int* Ab = adj + ((size_t)l * Bsz + b) * Ssz * Ssz;              \
            _Pragma("unroll")                                                     \
            for (int s = 0; s < 4; ++s)                                           \
                aiv[l][s] = Ab[(size_t)((J0) + 4 * jq + s) * Ssz + i0 + ii];      \
        }                                                                         \
        _Pragma("unroll")                                                         \
        for (int l = 0; l < Lsz; ++l) {                                           \
            const int* Ab = adj + ((size_t)l * Bsz + b) * Ssz * Ssz;              \
            aov[l] = *(const int4*)&Ab[(size_t)(i0 + rr) * Ssz + (J0) + 4 * c4];  \
        }                                                                         \
    }

    LOAD_CHUNK(0)

    for (int jc = 0; jc < Ssz / TJ; ++jc) {
        __syncthreads();   // previous chunk's fragment reads done

        // ---- WRITE phase: convert prefetched regs -> LDS (vmcnt waits land here)
        {
            short8 hi;
#pragma unroll
            for (int s = 0; s < 8; ++s) hi[s] = (short)f2bf(xv[s]);
            const int g = w ^ (lane & 7);
            *(short8*)(sm16 + XT16 + lane * 64 + g * 8) = hi;
        }
#pragma unroll
        for (int l = 0; l < Lsz; ++l) {
            s16x4 v;
#pragma unroll
            for (int s = 0; s < 4; ++s) v[s] = aiv[l][s] ? (short)0x3F80 : (short)0;
            const int g = (jq >> 1) ^ (ii & 7);
            *(s16x4*)(sm16 + AI16 + l * 2048 + ii * 64 + g * 8 + (jq & 1) * 4) = v;
        }
#pragma unroll
        for (int l = 0; l < Lsz; ++l) {
            s16x4 v;
            v[0] = aov[l].x ? (short)0x3F80 : (short)0;  v[1] = aov[l].y ? (short)0x3F80 : (short)0;
            v[2] = aov[l].z ? (short)0x3F80 : (short)0;  v[3] = aov[l].w ? (short)0x3F80 : (short)0;
            const int g = (c4 >> 1) ^ (rr & 7);
            *(s16x4*)(sm16 + AO16 + l * 2048 + rr * 64 + g * 8 + (c4 & 1) * 4) = v;
        }
        __syncthreads();

        // ---- issue next chunk's global loads BEFORE the MFMA phase (T14)
        if (jc + 1 < Ssz / TJ) LOAD_CHUNK((jc + 1) * TJ)

        // ---- 2 K-steps of 32 (current chunk, from LDS)
#pragma unroll
        for (int ks = 0; ks < 2; ++ks) {
            short8 bh[4];
#pragma unroll
            for (int nt = 0; nt < 4; ++nt) {
                const int d = nt * 16 + lm;
                const int g = (4 * ks + lg) ^ (d & 7);
                bh[nt] = *(const short8*)(sm16 + XT16 + d * 64 + g * 8);
            }
            const int i_loc = 16 * strip + lm;
            const int ga = (4 * ks + lg) ^ (i_loc & 7);
            const int a_off = (dir ? AO16 : AI16) + i_loc * 64 + ga * 8;
#pragma unroll
            for (int al = 0; al < 2; ++al) {
                const int l = 2 * lh + al;
                const short8 af = *(const short8*)(sm16 + a_off + l * 2048);
#pragma unroll
                for (int nt = 0; nt < 4; ++nt)
                    acc[al][nt] = __builtin_amdgcn_mfma_f32_16x16x32_bf16(af, bh[nt], acc[al][nt], 0, 0, 0);
                dacc[al] = __builtin_amdgcn_mfma_f32_16x16x32_bf16(af, ones, dacc[al], 0, 0, 0);
            }
        }
    }
#undef LOAD_CHUNK

    // ======== epilogue (round-8 verbatim): t = Y*W + deg*b; gate = Y*wg + deg*bg
    const int ei  = tid & 31;          // output row within tile
    const int ecg = tid >> 5;          // 4-column group 0..15
    float fin[4];
#pragma unroll
    for (int q = 0; q < 4; ++q) fin[q] = 0.f;

#pragma unroll
    for (int l = 0; l < Lsz; ++l) {
#pragma unroll
        for (int d2 = 0; d2 < 2; ++d2) {
            __syncthreads();   // previous consumers done before overwrite
            if (dir == d2 && lh == (l >> 1)) {   // this wave owns (strip, d2, label l)
                const int al = l & 1;
#pragma unroll
                for (int nt = 0; nt < 4; ++nt)
#pragma unroll
                    for (int r = 0; r < 4; ++r)
                        smf[YB_f + (16 * strip + 4 * lg + r) * YBs + nt * 16 + lm] = acc[al][nt][r];
                if (lm == 0)
#pragma unroll
                    for (int r = 0; r < 4; ++r)
                        smf[DG_f + 16 * strip + 4 * lg + r] = dacc[al][r];
            }
            // stage W (all threads, coalesced float4)
            const float* Wp = (d2 ? W_out : W_in) + l * Dsz * Dsz;
            {
                const int r = tid >> 3, c8 = tid & 7;
                *(float4*)&smf[WB_f + r * WBs + 8 * c8]     = *(const float4*)&Wp[r * Dsz + 8 * c8];
                *(float4*)&smf[WB_f + r * WBs + 8 * c8 + 4] = *(const float4*)&Wp[r * Dsz + 8 * c8 + 4];
            }
            const float* wgp = (d2 ? wg_out : wg_in) + l * Dsz;
            const float* bp  = (d2 ? b_out  : b_in)  + l * Dsz;
            if (tid < 64)        smf[WG_f + tid]      = wgp[tid];
            else if (tid < 128)  smf[BB_f + tid - 64] = bp[tid - 64];
            const float bgs = (d2 ? bg_out : bg_in)[l];
            __syncthreads();

            const float dg = smf[DG_f + ei];
            float t[4];
#pragma unroll
            for (int q = 0; q < 4; ++q) t[q] = dg * smf[BB_f + 4 * ecg + q];
            float gate = dg * bgs;
#pragma unroll 4
            for (int e = 0; e < 64; ++e) {
                const float yv = smf[YB_f + ei * YBs + e];
                gate += yv * smf[WG_f + e];
#pragma unroll
                for (int q = 0; q < 4; ++q) t[q] += yv * smf[WB_f + e * WBs + 4 * ecg + q];
            }
            const float sg = 1.f / (1.f + expf(-gate));
#pragma unroll
            for (int q = 0; q < 4; ++q) fin[q] += t[q] * sg;
        }
    }

    const float inv = 1.f / (3.f * nw[b]);
    const float4 xr = *(const float4*)&Xb[(size_t)(i0 + ei) * Dsz + 4 * ecg];
    float4 o;
    o.x = (xr.x + fin[0]) * inv;
    o.y = (xr.y + fin[1]) * inv;
    o.z = (xr.z + fin[2]) * inv;
    o.w = (xr.w + fin[3]) * inv;
    *(float4*)(out + ((size_t)b * Ssz + i0 + ei) * Dsz + 4 * ecg) = o;
}

extern "C" void kernel_launch(void* const* d_in, const int* in_sizes, int n_in,
                              void* d_out, int out_size, void* d_ws, size_t ws_size,
                              hipStream_t stream)
{
    const float* X      = (const float*)d_in[0];
    const int*   adj    = (const int*)  d_in[1];
    const float* nw     = (const float*)d_in[2];
    const float* W_in   = (const float*)d_in[3];
    const float* b_in   = (const float*)d_in[4];
    const float* wg_in  = (const float*)d_in[5];
    const float* bg_in  = (const float*)d_in[6];
    const float* W_out  = (const float*)d_in[7];
    const float* b_out  = (const float*)d_in[8];
    const float* wg_out = (const float*)d_in[9];
    const float* bg_out = (const float*)d_in[10];
    float* out = (float*)d_out;

    dim3 grid(Ssz / TI, Bsz);   // (16, 32) = 512 blocks
    dim3 block(512);
    hipLaunchKernelGGL(rfgcn_mfma, grid, block, 0, stream,
                       X, adj, nw, W_in, b_in, wg_in, bg_in,
                       W_out, b_out, wg_out, bg_out, out);
}